// Round 4
// baseline (132.184 us; speedup 1.0000x reference)
//
#include <hip/hip_runtime.h>

// FETANetwork: B=1024, N=64, F=128, H=8
// out[b,i] = (sum_{j!=i} (f_ij.wl + f_ji.wr))/63 + bsf + zeroth[b,i]
// f_ij = selu(selu(hi_i + hj_j + bf0) @ Wf1 + bf1)

#define SELU_ALPHA 1.6732632423543772f
#define SELU_SCALE 1.0507009873554805f

__device__ __forceinline__ float selu_f(float x) {
    // x>0: scale*x ; x<=0: scale*alpha*(exp(x)-1)
    float neg = fmaf(SELU_ALPHA, __expf(x), -SELU_ALPHA);
    return SELU_SCALE * (x > 0.0f ? x : neg);
}

// ---------------- Kernel 1: per-row projections + zeroth path ----------------
// 128 threads/block, one row of x (128 floats) per thread; 512 blocks.
__global__ __launch_bounds__(128) void feta_k1(
    const float* __restrict__ x,
    const float* __restrict__ Wz0, const float* __restrict__ bz0,
    const float* __restrict__ Wz1, const float* __restrict__ bz1,
    const float* __restrict__ wsz, const float* __restrict__ bsz,
    const float* __restrict__ Wf0, const float* __restrict__ bf0,
    float* __restrict__ hi_out, float* __restrict__ hj_out,
    float* __restrict__ z_out)
{
    __shared__ float xs[128 * 129];   // 128 rows, pad stride 129 (conflict-free)
    __shared__ float w0[128 * 8];     // Wz0
    __shared__ float wa[128 * 8];     // Wf0[:128]
    __shared__ float wb[128 * 8];     // Wf0[128:]

    const int t = threadIdx.x;
    const long long rowbase = (long long)blockIdx.x * 128;

    // cooperative coalesced load of 128x128 x-tile
    const float4* xin = (const float4*)(x + rowbase * 128);
    #pragma unroll
    for (int it = 0; it < 32; ++it) {
        int f4 = it * 128 + t;
        float4 v = xin[f4];
        int flat = f4 * 4;
        int r = flat >> 7;
        int c = flat & 127;
        float* dst = &xs[r * 129 + c];
        dst[0] = v.x; dst[1] = v.y; dst[2] = v.z; dst[3] = v.w;
    }
    for (int idx = t; idx < 1024; idx += 128) {
        w0[idx] = Wz0[idx];
        wa[idx] = Wf0[idx];
        wb[idx] = Wf0[1024 + idx];
    }
    __syncthreads();

    float az[8], aa[8], ab[8];
    #pragma unroll
    for (int c = 0; c < 8; ++c) { az[c] = bz0[c]; aa[c] = 0.f; ab[c] = 0.f; }

    const float* myrow = &xs[t * 129];
    for (int k = 0; k < 128; ++k) {
        float xk = myrow[k];
        #pragma unroll
        for (int c = 0; c < 8; ++c) {
            az[c] = fmaf(xk, w0[k * 8 + c], az[c]);
            aa[c] = fmaf(xk, wa[k * 8 + c], aa[c]);
            ab[c] = fmaf(xk, wb[k * 8 + c], ab[c]);
        }
    }

    const long long gr = rowbase + t;
    float* hip = hi_out + gr * 8;
    float* hjp = hj_out + gr * 8;
    #pragma unroll
    for (int c = 0; c < 8; ++c) {
        hip[c] = aa[c] + bf0[c];   // fold bf0 into hi
        hjp[c] = ab[c];
    }

    // zeroth path: h0 = selu(az); h1 = selu(h0@Wz1+bz1); z = selu(h1.wsz+bsz)
    float h0[8];
    #pragma unroll
    for (int c = 0; c < 8; ++c) h0[c] = selu_f(az[c]);
    float zacc = bsz[0];
    #pragma unroll
    for (int c = 0; c < 8; ++c) {
        float s = bz1[c];
        #pragma unroll
        for (int r = 0; r < 8; ++r) s = fmaf(h0[r], Wz1[r * 8 + c], s);
        zacc = fmaf(selu_f(s), wsz[c], zacc);
    }
    z_out[gr] = selu_f(zacc);
}

// ---------------- Kernel 2: pair network + masked mean ----------------
// One block per batch (1024 blocks), 256 threads. Thread (w,l): j=l fixed,
// i = w*16+k for k=0..15. Row-sums via padded LDS matrix; col-sums in-register.
__global__ __launch_bounds__(256) void feta_k2(
    const float* __restrict__ hi, const float* __restrict__ hj,
    const float* __restrict__ z,
    const float* __restrict__ Wf1, const float* __restrict__ bf1,
    const float* __restrict__ wsf, const float* __restrict__ bsf,
    float* __restrict__ out)
{
    __shared__ float his[64 * 8];     // hi'(+bf0) rows for this batch
    __shared__ float ts[64 * 65];     // t_ij matrix, pad 65 (2-way only)
    __shared__ float cup[4 * 64];     // column partials per wave
    __shared__ float rsp[4 * 64];     // row partials per wave

    const int b = blockIdx.x;
    const int t = threadIdx.x;
    const int w = t >> 6;
    const int l = t & 63;
    const long long base = (long long)b * 64 * 8;

    if (t < 128) ((float4*)his)[t] = ((const float4*)(hi + base))[t];

    // my column's hj row (j = l), coalesced 2x float4
    float hjr[8];
    {
        const float4* hp = (const float4*)(hj + base + l * 8);
        float4 v0 = hp[0], v1 = hp[1];
        hjr[0] = v0.x; hjr[1] = v0.y; hjr[2] = v0.z; hjr[3] = v0.w;
        hjr[4] = v1.x; hjr[5] = v1.y; hjr[6] = v1.z; hjr[7] = v1.w;
    }

    // uniform weights -> scalar loads
    float W[64], bf[8], wl[8], wr[8];
    #pragma unroll
    for (int i = 0; i < 64; ++i) W[i] = Wf1[i];
    #pragma unroll
    for (int c = 0; c < 8; ++c) { bf[c] = bf1[c]; wl[c] = wsf[c]; wr[c] = wsf[8 + c]; }
    const float bsfv = bsf[0];
    __syncthreads();

    float cu_acc = 0.f;
    for (int k = 0; k < 16; ++k) {
        const int i = w * 16 + k;                 // uniform within wave
        const float* hrow = &his[i * 8];          // LDS broadcast
        float g[8];
        #pragma unroll
        for (int c = 0; c < 8; ++c) g[c] = selu_f(hrow[c] + hjr[c]);
        float tt = 0.f, uu = 0.f;
        #pragma unroll
        for (int c = 0; c < 8; ++c) {
            float s = bf[c];
            #pragma unroll
            for (int r = 0; r < 8; ++r) s = fmaf(g[r], W[r * 8 + c], s);
            float fv = selu_f(s);
            tt = fmaf(fv, wl[c], tt);
            uu = fmaf(fv, wr[c], uu);
        }
        if (i == l) { tt = 0.f; uu = 0.f; }       // mask diagonal
        cu_acc += uu;
        ts[i * 65 + l] = tt;
    }
    cup[w * 64 + l] = cu_acc;
    __syncthreads();

    // row partial: thread (w,l) sums row l over j in [w*16, w*16+16)
    float rp = 0.f;
    #pragma unroll
    for (int m = 0; m < 16; ++m) rp += ts[l * 65 + w * 16 + m];
    rsp[w * 64 + l] = rp;
    __syncthreads();

    if (t < 64) {
        float rsum = rsp[t] + rsp[64 + t] + rsp[128 + t] + rsp[192 + t];
        float csum = cup[t] + cup[64 + t] + cup[128 + t] + cup[192 + t];
        out[(long long)b * 64 + t] =
            (rsum + csum) * (1.0f / 63.0f) + bsfv + z[(long long)b * 64 + t];
    }
}

extern "C" void kernel_launch(void* const* d_in, const int* in_sizes, int n_in,
                              void* d_out, int out_size, void* d_ws, size_t ws_size,
                              hipStream_t stream) {
    const float* x   = (const float*)d_in[0];
    const float* Wz0 = (const float*)d_in[1];
    const float* bz0 = (const float*)d_in[2];
    const float* Wz1 = (const float*)d_in[3];
    const float* bz1 = (const float*)d_in[4];
    const float* wsz = (const float*)d_in[5];
    const float* bsz = (const float*)d_in[6];
    const float* Wf0 = (const float*)d_in[7];
    const float* bf0 = (const float*)d_in[8];
    const float* Wf1 = (const float*)d_in[9];
    const float* bf1 = (const float*)d_in[10];
    const float* wsf = (const float*)d_in[11];
    const float* bsf = (const float*)d_in[12];
    float* out = (float*)d_out;

    float* hi_ws = (float*)d_ws;                 // 65536*8 floats (hi + bf0)
    float* hj_ws = hi_ws + 65536 * 8;            // 65536*8 floats
    float* z_ws  = hj_ws + 65536 * 8;            // 65536 floats

    feta_k1<<<512, 128, 0, stream>>>(x, Wz0, bz0, Wz1, bz1, wsz, bsz,
                                     Wf0, bf0, hi_ws, hj_ws, z_ws);
    feta_k2<<<1024, 256, 0, stream>>>(hi_ws, hj_ws, z_ws, Wf1, bf1, wsf, bsf, out);
}

// Round 7
// 118.233 us; speedup vs baseline: 1.1180x; 1.1180x over previous
//
#include <hip/hip_runtime.h>

// FETANetwork fused: B=1024, N=64, F=128, H=8. One block per batch.
// out[b,i] = (sum_{j!=i} f_ij.wl + sum_{j!=i} f_ji.wr)/63 + bsf + zeroth[b,i]
// f_ij = selu(selu(hi_i + hj_j) @ Wf1 + bf1),  hi = x@Wa + bf0, hj = x@Wb
// SELU outer scale folded into Wf1 and wsf (sel() = unscaled selu).

#define SELU_ALPHA 1.6732632423543772f
#define SELU_SCALE 1.0507009873554805f

__device__ __forceinline__ float selu_full(float x) {
    float neg = fmaf(SELU_ALPHA, __expf(x), -SELU_ALPHA);
    return SELU_SCALE * (x > 0.0f ? x : neg);
}
__device__ __forceinline__ float sel_unscaled(float x) {   // selu(x) / SELU_SCALE
    float neg = fmaf(SELU_ALPHA, __expf(x), -SELU_ALPHA);
    return x > 0.0f ? x : neg;
}

__global__ __launch_bounds__(256) void feta_fused(
    const float* __restrict__ x,
    const float* __restrict__ Wz0, const float* __restrict__ bz0,
    const float* __restrict__ Wz1, const float* __restrict__ bz1,
    const float* __restrict__ wsz, const float* __restrict__ bsz,
    const float* __restrict__ Wf0, const float* __restrict__ bf0,
    const float* __restrict__ Wf1, const float* __restrict__ bf1,
    const float* __restrict__ wsf, const float* __restrict__ bsf,
    float* __restrict__ out)
{
    // smem: phase1 = xs[64][129] (33 KB); phase2 = ts[64][65] + cup[256] + rsp[256]
    __shared__ float smem[64 * 129];
    __shared__ float his[64 * 12];   // stride 12: 16B-aligned rows, cheap broadcast b128
    __shared__ float hjs[64 * 12];
    __shared__ float zs[64];

    const int b = blockIdx.x;
    const int t = threadIdx.x;
    const int w = t >> 6;
    const int l = t & 63;

    // ---- stage x tile (64 x 128), row-major stride 129; coalesced global float4,
    //      conflict-free b128 LDS writes (consecutive lanes -> consecutive cols)
    {
        const float4* xin = (const float4*)(x + (long long)b * 8192);
        #pragma unroll
        for (int i = 0; i < 8; ++i) {
            int f4 = i * 256 + t;            // 0..2047
            float4 v = xin[f4];
            int r  = f4 >> 5;                // 32 float4 per row
            int kq = f4 & 31;
            *(float4*)&smem[r * 129 + kq * 4] = v;
        }
    }
    __syncthreads();

    // ---- phase 1: per-wave roles. Lane = row. Weights via wave-uniform (s_load)
    //      global reads; x column reads from LDS are 2-lanes/bank (free).
    const float* xr = &smem[l * 129];
    if (w == 0) {
        // az = x@Wz0 + bz0, then full zeroth path in-register
        float acc[8];
        #pragma unroll
        for (int c = 0; c < 8; ++c) acc[c] = bz0[c];
        #pragma unroll 8
        for (int k = 0; k < 128; ++k) {
            float xk = xr[k];
            #pragma unroll
            for (int c = 0; c < 8; ++c) acc[c] = fmaf(xk, Wz0[k * 8 + c], acc[c]);
        }
        float h0[8];
        #pragma unroll
        for (int c = 0; c < 8; ++c) h0[c] = selu_full(acc[c]);
        float zacc = bsz[0];
        #pragma unroll
        for (int c = 0; c < 8; ++c) {
            float s = bz1[c];
            #pragma unroll
            for (int r = 0; r < 8; ++r) s = fmaf(h0[r], Wz1[r * 8 + c], s);
            zacc = fmaf(selu_full(s), wsz[c], zacc);
        }
        zs[l] = selu_full(zacc);
    } else if (w == 1) {
        // hi = x@Wa + bf0
        float acc[8];
        #pragma unroll
        for (int c = 0; c < 8; ++c) acc[c] = bf0[c];
        #pragma unroll 8
        for (int k = 0; k < 128; ++k) {
            float xk = xr[k];
            #pragma unroll
            for (int c = 0; c < 8; ++c) acc[c] = fmaf(xk, Wf0[k * 8 + c], acc[c]);
        }
        #pragma unroll
        for (int c = 0; c < 8; ++c) his[l * 12 + c] = acc[c];
    } else {
        // hj = x@Wb, split: wave2 -> cols 0..3, wave3 -> cols 4..7
        const int c0 = (w == 3) ? 4 : 0;
        const float* wb = Wf0 + 1024 + c0;
        float acc[4];
        #pragma unroll
        for (int c = 0; c < 4; ++c) acc[c] = 0.f;
        #pragma unroll 8
        for (int k = 0; k < 128; ++k) {
            float xk = xr[k];
            #pragma unroll
            for (int c = 0; c < 4; ++c) acc[c] = fmaf(xk, wb[k * 8 + c], acc[c]);
        }
        #pragma unroll
        for (int c = 0; c < 4; ++c) hjs[l * 12 + c0 + c] = acc[c];
    }

    // phase-2 weights (uniform; scale folded). No LDS hazard — load before barrier.
    float W[64], bfv[8], wl[8], wr[8];
    #pragma unroll
    for (int i = 0; i < 64; ++i) W[i] = SELU_SCALE * Wf1[i];
    #pragma unroll
    for (int c = 0; c < 8; ++c) {
        bfv[c] = bf1[c];
        wl[c]  = SELU_SCALE * wsf[c];
        wr[c]  = SELU_SCALE * wsf[8 + c];
    }
    const float bsfv = bsf[0];
    __syncthreads();

    // ---- phase 2: thread (w,l): j = l, i = w*16+k for k=0..15
    float hjr[8];
    #pragma unroll
    for (int c = 0; c < 8; ++c) hjr[c] = hjs[l * 12 + c];

    float* ts  = smem;             // [64][65], fits in dead xs space
    float* cup = smem + 64 * 65;   // [4][64]
    float* rsp = cup + 256;        // [4][64]

    float cu_acc = 0.f;
    for (int k = 0; k < 16; ++k) {
        const int i = w * 16 + k;               // wave-uniform
        const float* hrow = &his[i * 12];       // LDS broadcast (16B-aligned)
        float g[8];
        #pragma unroll
        for (int c = 0; c < 8; ++c) g[c] = sel_unscaled(hrow[c] + hjr[c]);
        float tt = 0.f, uu = 0.f;
        #pragma unroll
        for (int c = 0; c < 8; ++c) {
            float s = bfv[c];
            #pragma unroll
            for (int r = 0; r < 8; ++r) s = fmaf(g[r], W[r * 8 + c], s);
            float fv = sel_unscaled(s);
            tt = fmaf(fv, wl[c], tt);
            uu = fmaf(fv, wr[c], uu);
        }
        if (i == l) { tt = 0.f; uu = 0.f; }     // diagonal mask
        cu_acc += uu;
        ts[i * 65 + l] = tt;
    }
    cup[w * 64 + l] = cu_acc;
    __syncthreads();

    // row partials: thread (w,l) sums row l over j in [w*16, w*16+16)
    float rp = 0.f;
    #pragma unroll
    for (int m = 0; m < 16; ++m) rp += ts[l * 65 + w * 16 + m];
    rsp[w * 64 + l] = rp;
    __syncthreads();

    if (t < 64) {
        float rsum = rsp[t] + rsp[64 + t] + rsp[128 + t] + rsp[192 + t];
        float csum = cup[t] + cup[64 + t] + cup[128 + t] + cup[192 + t];
        out[(long long)b * 64 + t] =
            (rsum + csum) * (1.0f / 63.0f) + bsfv + zs[t];
    }
}

extern "C" void kernel_launch(void* const* d_in, const int* in_sizes, int n_in,
                              void* d_out, int out_size, void* d_ws, size_t ws_size,
                              hipStream_t stream) {
    const float* x   = (const float*)d_in[0];
    const float* Wz0 = (const float*)d_in[1];
    const float* bz0 = (const float*)d_in[2];
    const float* Wz1 = (const float*)d_in[3];
    const float* bz1 = (const float*)d_in[4];
    const float* wsz = (const float*)d_in[5];
    const float* bsz = (const float*)d_in[6];
    const float* Wf0 = (const float*)d_in[7];
    const float* bf0 = (const float*)d_in[8];
    const float* Wf1 = (const float*)d_in[9];
    const float* bf1 = (const float*)d_in[10];
    const float* wsf = (const float*)d_in[11];
    const float* bsf = (const float*)d_in[12];
    float* out = (float*)d_out;

    feta_fused<<<1024, 256, 0, stream>>>(x, Wz0, bz0, Wz1, bz1, wsz, bsz,
                                         Wf0, bf0, Wf1, bf1, wsf, bsf, out);
}